// Round 1
// baseline (486.948 us; speedup 1.0000x reference)
//
#include <hip/hip_runtime.h>

// LIF charge->fire->hard-reset scan over T timesteps.
// x_seq: [T, N] fp32 (T=4 outermost), out: [T, N] fp32 spikes in {0,1}.
// v0 = 0; v_charged = v + (x - v)/2; spike = (v_charged >= 1); v_next = spike ? 0 : v_charged.
// Memory-bound: each thread owns 4 consecutive neurons (float4), carries v in
// registers across the T loop -> perfectly coalesced, minimal HBM traffic.

constexpr int T_STEPS = 4;

__global__ __launch_bounds__(256) void lif_kernel(const float4* __restrict__ x,
                                                  float4* __restrict__ out,
                                                  long long n4) {
    long long i = (long long)blockIdx.x * blockDim.x + threadIdx.x;
    if (i >= n4) return;

    float4 v = make_float4(0.f, 0.f, 0.f, 0.f);

#pragma unroll
    for (int t = 0; t < T_STEPS; ++t) {
        float4 xv = x[(long long)t * n4 + i];
        float4 s;

        // Exact op order as reference: v_charged = v + (x - v) / 2.0f
        v.x = v.x + (xv.x - v.x) * 0.5f;
        v.y = v.y + (xv.y - v.y) * 0.5f;
        v.z = v.z + (xv.z - v.z) * 0.5f;
        v.w = v.w + (xv.w - v.w) * 0.5f;

        s.x = (v.x >= 1.0f) ? 1.0f : 0.0f;
        s.y = (v.y >= 1.0f) ? 1.0f : 0.0f;
        s.z = (v.z >= 1.0f) ? 1.0f : 0.0f;
        s.w = (v.w >= 1.0f) ? 1.0f : 0.0f;

        // hard reset (detach): v_next = spike ? 0 : v_charged
        v.x = (s.x != 0.0f) ? 0.0f : v.x;
        v.y = (s.y != 0.0f) ? 0.0f : v.y;
        v.z = (s.z != 0.0f) ? 0.0f : v.z;
        v.w = (s.w != 0.0f) ? 0.0f : v.w;

        out[(long long)t * n4 + i] = s;
    }
}

extern "C" void kernel_launch(void* const* d_in, const int* in_sizes, int n_in,
                              void* d_out, int out_size, void* d_ws, size_t ws_size,
                              hipStream_t stream) {
    const float* x = (const float*)d_in[0];
    float* out = (float*)d_out;

    long long total = (long long)in_sizes[0];   // T * N
    long long n = total / T_STEPS;              // neurons per timestep
    long long n4 = n / 4;                       // float4 groups (N divisible by 4: 768 inner dim)

    int block = 256;
    long long grid = (n4 + block - 1) / block;

    lif_kernel<<<(int)grid, block, 0, stream>>>((const float4*)x, (float4*)out, n4);
}

// Round 2
// 480.082 us; speedup vs baseline: 1.0143x; 1.0143x over previous
//
#include <hip/hip_runtime.h>

// LIF charge->fire->hard-reset scan over T=4 timesteps.
// x_seq: [T, N] fp32 (T outermost), out: [T, N] fp32 spikes in {0,1}.
// v0 = 0; v_charged = v + (x - v)*0.5f; spike = (v_charged >= 1); v = spike ? 0 : v_charged.
//
// Pure streaming (620 MB compulsory traffic). Each thread owns TWO float4
// groups (i and i+half), carrying v in registers across T:
//  - 8 nontemporal dwordx4 loads in flight per thread -> high MLP
//  - nontemporal stores: out is write-once, never re-read -> skip L2/L3 alloc
//  - all accesses coalesced: lane i -> 16B at base + i*16

typedef float f4 __attribute__((ext_vector_type(4)));

constexpr int T_STEPS = 4;

__global__ __launch_bounds__(256) void lif_kernel(const f4* __restrict__ x,
                                                  f4* __restrict__ out,
                                                  long long n4, long long half) {
    long long i = (long long)blockIdx.x * blockDim.x + threadIdx.x;
    if (i >= half) return;
    long long j = i + half;

    f4 v0 = {0.f, 0.f, 0.f, 0.f};
    f4 v1 = {0.f, 0.f, 0.f, 0.f};

#pragma unroll
    for (int t = 0; t < T_STEPS; ++t) {
        f4 x0 = __builtin_nontemporal_load(x + (long long)t * n4 + i);
        f4 x1 = __builtin_nontemporal_load(x + (long long)t * n4 + j);
        f4 s0, s1;

#pragma unroll
        for (int k = 0; k < 4; ++k) {
            // exact reference op order: v_charged = v + (x - v) / 2
            v0[k] = v0[k] + (x0[k] - v0[k]) * 0.5f;
            float sp0 = (v0[k] >= 1.0f) ? 1.0f : 0.0f;
            s0[k] = sp0;
            v0[k] = (sp0 != 0.0f) ? 0.0f : v0[k];

            v1[k] = v1[k] + (x1[k] - v1[k]) * 0.5f;
            float sp1 = (v1[k] >= 1.0f) ? 1.0f : 0.0f;
            s1[k] = sp1;
            v1[k] = (sp1 != 0.0f) ? 0.0f : v1[k];
        }

        __builtin_nontemporal_store(s0, out + (long long)t * n4 + i);
        __builtin_nontemporal_store(s1, out + (long long)t * n4 + j);
    }
}

extern "C" void kernel_launch(void* const* d_in, const int* in_sizes, int n_in,
                              void* d_out, int out_size, void* d_ws, size_t ws_size,
                              hipStream_t stream) {
    const float* x = (const float*)d_in[0];
    float* out = (float*)d_out;

    long long total = (long long)in_sizes[0];   // T * N
    long long n = total / T_STEPS;              // neurons per timestep (19,365,888)
    long long n4 = n / 4;                       // float4 groups per timestep (4,841,472)
    long long half = n4 / 2;                    // 2,420,736 (divides evenly)

    int block = 256;
    long long grid = (half + block - 1) / block;  // 9456 blocks

    lif_kernel<<<(int)grid, block, 0, stream>>>((const f4*)x, (f4*)out, n4, half);
}